// Round 1
// 497.879 us; speedup vs baseline: 1.0722x; 1.0722x over previous
//
#include <hip/hip_runtime.h>

typedef _Float16 half_t;
typedef _Float16 half2_t __attribute__((ext_vector_type(2)));
union pk_u { unsigned int u; half2_t h; };

#define EMB 64
#define NLAYERS 3
#define BSH2 9
#define BW2 512            // nodes per coarse bucket
#define NB2MAX 512         // max bucket count (N<=262144)
#define CAP 20480          // padded region per bucket (avg 17065 edges, +20%)
#define P1_BATCH 4096
#define P1_TH 512
#define P1_EPT 8           // edges per thread in part_kernel (4096/512)
#define BINTH 1024

// ---- 512-entry exclusive scan, first 256 threads active, all threads hit barriers ----
__device__ inline void scan_512w(int* __restrict__ hist, int* __restrict__ lstart,
                                 int* __restrict__ pair) {
    int t = threadIdx.x;
    int a0 = 0, a1 = 0;
    if (t < 256) { a0 = hist[2 * t]; a1 = hist[2 * t + 1]; pair[t] = a0 + a1; }
    __syncthreads();
    for (int off = 1; off < 256; off <<= 1) {
        int u = 0;
        if (t < 256 && t >= off) u = pair[t - off];
        __syncthreads();
        if (t < 256) pair[t] += u;
        __syncthreads();
    }
    if (t < 256) {
        lstart[2 * t]     = pair[t] - a0 - a1;
        lstart[2 * t + 1] = pair[t] - a1;
    }
    __syncthreads();
}

// ---- pass 1: partition edges into coarse buckets, LDS-sorted dense writes ----
// 512 threads: halves serial rounds vs 256, 4 blocks/CU -> 32 waves/CU resident.
__global__ __launch_bounds__(512) void part_kernel(
        const int* __restrict__ row, const int* __restrict__ col,
        int* __restrict__ gcount, int* __restrict__ tmp, int E, int nb2) {
    __shared__ int hist[NB2MAX];
    __shared__ int lstart[NB2MAX];
    __shared__ int gbase[NB2MAX];
    __shared__ int pair[256];
    __shared__ int srec[P1_BATCH];            // batch sorted by bucket
    __shared__ unsigned short sbuck[P1_BATCH];

    int base = blockIdx.x * P1_BATCH;
    int nE = min(P1_BATCH, E - base);

    for (int i = threadIdx.x; i < NB2MAX; i += P1_TH) hist[i] = 0;
    __syncthreads();

    // histogram (keep cols in registers)
    int myc[P1_EPT];
    #pragma unroll
    for (int k = 0; k < P1_EPT; ++k) {
        int idx = base + (k << 9) + threadIdx.x;     // coalesced
        int c = (idx < E) ? col[idx] : -1;
        myc[k] = c;
        if (c >= 0) atomicAdd(&hist[c >> BSH2], 1);
    }
    __syncthreads();

    scan_512w(hist, lstart, pair);

    // reserve global space: one atomic per (block,bucket)
    for (int b = threadIdx.x; b < nb2; b += P1_TH) {
        int c = hist[b];
        int off = 0;
        if (c > 0) off = atomicAdd(&gcount[b], c);
        gbase[b] = b * CAP + off - lstart[b];        // dest = gbase[b]+sorted_idx
    }
    __syncthreads();
    for (int b = threadIdx.x; b < NB2MAX; b += P1_TH) hist[b] = lstart[b];  // cursors
    __syncthreads();

    // sort batch into LDS by bucket
    #pragma unroll
    for (int k = 0; k < P1_EPT; ++k) {
        int idx = base + (k << 9) + threadIdx.x;
        if (idx < E) {
            int c = myc[k];
            int b = c >> BSH2;
            int r = row[idx];
            int pos = atomicAdd(&hist[b], 1);
            srec[pos] = (r << BSH2) | (c & (BW2 - 1));
            sbuck[pos] = (unsigned short)b;
        }
    }
    __syncthreads();

    // dense write-out: consecutive slots -> consecutive global addresses per run
    for (int i = threadIdx.x; i < nE; i += P1_TH)
        tmp[gbase[sbuck[i]] + i] = srec[i];
}

// ---- pass 2: one block per bucket; emits sd/dis, fine-sorted eg (src<<4), AND the
//      fused init (out = x, s0 = fp16(dis*x)) for its 512 nodes ----
// 1024 threads: was 256 (1 wave/SIMD -> latency-exposed rounds); now 4x TLP.
__global__ __launch_bounds__(1024) void bin_kernel(
        const int* __restrict__ tmp, const int* __restrict__ gcount,
        int* __restrict__ eg, int2* __restrict__ sd, float* __restrict__ dis,
        const float4* __restrict__ uev, const float4* __restrict__ mev,
        float4* __restrict__ outv, uint2* __restrict__ s0v,
        int n_users, int N) {
    __shared__ int hist[BW2];
    __shared__ int lstart[BW2];
    __shared__ int pair[256];
    __shared__ float sdis[BW2];
    int b = blockIdx.x;
    int cnt = gcount[b];
    int rbase = b * CAP;
    int c0 = b << BSH2;
    int nc = min(BW2, N - c0);

    for (int i = threadIdx.x; i < BW2; i += BINTH) hist[i] = 0;
    __syncthreads();
    for (int i = threadIdx.x; i < cnt; i += BINTH)
        atomicAdd(&hist[tmp[rbase + i] & (BW2 - 1)], 1);
    __syncthreads();

    scan_512w(hist, lstart, pair);

    // per-node metadata
    for (int c = threadIdx.x; c < nc; c += BINTH) {
        int d = hist[c];
        float dn = (d > 0) ? rsqrtf((float)d) : 0.0f;
        sd[c0 + c] = make_int2(rbase + lstart[c], d);
        dis[c0 + c] = dn;
        sdis[c] = dn;
    }
    __syncthreads();
    for (int i = threadIdx.x; i < BW2; i += BINTH) hist[i] = lstart[i];  // cursors
    __syncthreads();

    // scatter src ids (pre-shifted <<4 for gather's byte addressing)
    for (int i = threadIdx.x; i < cnt; i += BINTH) {
        int v = tmp[rbase + i];
        int pos = atomicAdd(&hist[v & (BW2 - 1)], 1);
        eg[rbase + pos] = (v >> BSH2) << 4;
    }

    // fused init for this bucket's nodes: out = x, s0 = fp16(dis*x)
    for (int i = threadIdx.x; i < nc * 16; i += BINTH) {
        int loc = i >> 4;
        int node = c0 + loc;
        int q = i & 15;
        const float4* src = (node < n_users) ? (uev + (long long)node * 16)
                                             : (mev + (long long)(node - n_users) * 16);
        float4 v = src[q];
        outv[(long long)node * 16 + q] = v;
        float dn = sdis[loc];
        pk_u w0, w1;
        w0.h[0] = (half_t)(v.x * dn); w0.h[1] = (half_t)(v.y * dn);
        w1.h[0] = (half_t)(v.z * dn); w1.h[1] = (half_t)(v.w * dn);
        s0v[(long long)node * 16 + q] = make_uint2(w0.u, w1.u);
    }
}

// ---------------- pull propagate, quad-dim / quad-edge, packed fp16 acc --------
// lane l: p=l&15 owns dims 4p..4p+3 (one uint2/row); h=l>>4 owns edge (j+4k+h).
// Single predicated 32-edge-wide loop: 8 row-loads in flight, no serial tail.
// (mean degree 33.3 -> ~1.6 latency rounds/wave vs ~3 before)
template <bool LAST>
__global__ __launch_bounds__(256) void gather_kernel(
        const int* __restrict__ eg, const int2* __restrict__ sd,
        const float* __restrict__ dis,
        const uint2* __restrict__ tab, uint2* __restrict__ sB,
        float4* __restrict__ outv, float scale, int N) {
    int wave = blockIdx.x * (blockDim.x >> 6) + (threadIdx.x >> 6);
    if (wave >= N) return;
    int l = threadIdx.x & 63;
    int p = l & 15;
    int h = l >> 4;
    unsigned pb = (unsigned)p << 3;          // byte offset of this lane's uint2
    const char* tb = (const char*)tab;

    int2 se = sd[wave];
    int j = se.x;
    int e = se.x + se.y;
    pk_u a01, a23;
    a01.u = 0; a23.u = 0;                    // packed fp16 zeros

    for (; j < e; j += 32) {
        int last = e - 1;
        int r[8];
        bool ok[8];
        #pragma unroll
        for (int k = 0; k < 8; ++k) {
            int idx = j + (k << 2) + h;
            ok[k] = idx < e;
            r[k] = eg[min(idx, last)];       // clamped lanes re-read last row (broadcast)
        }
        #pragma unroll
        for (int k = 0; k < 8; ++k) {
            // eg stores src<<4; (r<<3)+pb = src*128 + p*8 (32-bit SADDR form)
            uint2 v = *(const uint2*)(tb + ((unsigned)(r[k] << 3) + pb));
            pk_u t;
            t.u = ok[k] ? v.x : 0u; a01.h += t.h;
            t.u = ok[k] ? v.y : 0u; a23.h += t.h;
        }
    }

    // reduce across the 4 edge-phases (packed)
    pk_u t;
    t.u = (unsigned int)__shfl_xor((int)a01.u, 16); a01.h += t.h;
    t.u = (unsigned int)__shfl_xor((int)a01.u, 32); a01.h += t.h;
    t.u = (unsigned int)__shfl_xor((int)a23.u, 16); a23.h += t.h;
    t.u = (unsigned int)__shfl_xor((int)a23.u, 32); a23.h += t.h;

    if (h == 0) {
        float dc = dis[wave];
        float g0 = dc * (float)a01.h[0];
        float g1 = dc * (float)a01.h[1];
        float g2 = dc * (float)a23.h[0];
        float g3 = dc * (float)a23.h[1];
        long long o = (long long)wave * 16 + p;
        float4 v = outv[o];
        v.x = (v.x + g0) * scale;
        v.y = (v.y + g1) * scale;
        v.z = (v.z + g2) * scale;
        v.w = (v.w + g3) * scale;
        outv[o] = v;
        if (!LAST) {
            pk_u w0, w1;
            w0.h[0] = (half_t)(dc * g0); w0.h[1] = (half_t)(dc * g1);
            w1.h[0] = (half_t)(dc * g2); w1.h[1] = (half_t)(dc * g3);
            sB[o] = make_uint2(w0.u, w1.u);
        }
    }
}

extern "C" void kernel_launch(void* const* d_in, const int* in_sizes, int n_in,
                              void* d_out, int out_size, void* d_ws, size_t ws_size,
                              hipStream_t stream) {
    const int*   edge = (const int*)d_in[0];    // [2, E]: row then col
    const float* ue   = (const float*)d_in[2];
    const float* me   = (const float*)d_in[3];
    float*       out  = (float*)d_out;

    const int E        = in_sizes[0] / 2;
    const int n_users  = in_sizes[2] / EMB;
    const int n_movies = in_sizes[3] / EMB;
    const int N        = n_users + n_movies;
    const int* row = edge;
    const int* col = edge + E;
    const int nb2 = (N + BW2 - 1) >> BSH2;      // 293 coarse buckets

    // workspace layout
    char* ws = (char*)d_ws;
    auto align_up = [](size_t v) { return (v + 255) & ~(size_t)255; };
    int*    gcount = (int*)ws;    ws += align_up((size_t)NB2MAX * sizeof(int));
    int2*   sd     = (int2*)ws;   ws += align_up((size_t)N * sizeof(int2));
    float*  dis    = (float*)ws;  ws += align_up((size_t)N * sizeof(float));
    int*    tmp    = (int*)ws;    ws += align_up((size_t)nb2 * CAP * sizeof(int));
    int*    eg     = (int*)ws;    ws += align_up((size_t)nb2 * CAP * sizeof(int));
    half_t* sA     = (half_t*)ws; ws += align_up((size_t)N * EMB * sizeof(half_t));
    half_t* sB     = (half_t*)ws; ws += align_up((size_t)N * EMB * sizeof(half_t));

    // two-pass counting sort -> CSR (deg/dis/init all fused into pass 2)
    hipMemsetAsync(gcount, 0, (size_t)NB2MAX * sizeof(int), stream);
    part_kernel<<<(E + P1_BATCH - 1) / P1_BATCH, P1_TH, 0, stream>>>(
        row, col, gcount, tmp, E, nb2);
    bin_kernel<<<nb2, BINTH, 0, stream>>>(
        tmp, gcount, eg, sd, dis,
        (const float4*)ue, (const float4*)me, (float4*)out, (uint2*)sA,
        n_users, N);

    // 3 propagation layers (atomic-free pull, packed fp16)
    const int waves_per_block = 4;   // 256 threads
    const int gblocks = (N + waves_per_block - 1) / waves_per_block;
    gather_kernel<false><<<gblocks, 256, 0, stream>>>(
        eg, sd, dis, (const uint2*)sA, (uint2*)sB, (float4*)out, 1.0f, N);
    gather_kernel<false><<<gblocks, 256, 0, stream>>>(
        eg, sd, dis, (const uint2*)sB, (uint2*)sA, (float4*)out, 1.0f, N);
    gather_kernel<true><<<gblocks, 256, 0, stream>>>(
        eg, sd, dis, (const uint2*)sA, (uint2*)sB, (float4*)out,
        1.0f / (NLAYERS + 1), N);
}

// Round 2
// 492.893 us; speedup vs baseline: 1.0831x; 1.0101x over previous
//
#include <hip/hip_runtime.h>

typedef _Float16 half_t;
typedef _Float16 half2_t __attribute__((ext_vector_type(2)));
union pk_u { unsigned int u; half2_t h; };

#define EMB 64
#define NLAYERS 3
#define BSH2 9
#define BW2 512            // nodes per coarse bucket
#define NB2MAX 512         // max bucket count (N<=262144)
#define CAP 20480          // tmp region per bucket (avg 17065 edges, +20%)
#define EGCAP 28672        // eg region per bucket (padded lists: avg 25.3K + slack)
#define P1_BATCH 4096
#define P1_TH 512
#define P1_EPT 8           // edges per thread in part_kernel (4096/512)
#define BINTH 1024

// ---- 512-entry exclusive scan of in[] -> lstart[]; first 256 threads active ----
__device__ inline void scan_512w(const int* __restrict__ in, int* __restrict__ lstart,
                                 int* __restrict__ pair) {
    int t = threadIdx.x;
    int a0 = 0, a1 = 0;
    if (t < 256) { a0 = in[2 * t]; a1 = in[2 * t + 1]; pair[t] = a0 + a1; }
    __syncthreads();
    for (int off = 1; off < 256; off <<= 1) {
        int u = 0;
        if (t < 256 && t >= off) u = pair[t - off];
        __syncthreads();
        if (t < 256) pair[t] += u;
        __syncthreads();
    }
    if (t < 256) {
        lstart[2 * t]     = pair[t] - a0 - a1;
        lstart[2 * t + 1] = pair[t] - a1;
    }
    __syncthreads();
}

// ---- pass 1: partition edges into coarse buckets, LDS-sorted dense writes ----
__global__ __launch_bounds__(512) void part_kernel(
        const int* __restrict__ row, const int* __restrict__ col,
        int* __restrict__ gcount, int* __restrict__ tmp, int E, int nb2) {
    __shared__ int hist[NB2MAX];
    __shared__ int lstart[NB2MAX];
    __shared__ int gbase[NB2MAX];
    __shared__ int pair[256];
    __shared__ int srec[P1_BATCH];            // batch sorted by bucket
    __shared__ unsigned short sbuck[P1_BATCH];

    int base = blockIdx.x * P1_BATCH;
    int nE = min(P1_BATCH, E - base);

    for (int i = threadIdx.x; i < NB2MAX; i += P1_TH) hist[i] = 0;
    __syncthreads();

    // histogram (keep cols in registers)
    int myc[P1_EPT];
    #pragma unroll
    for (int k = 0; k < P1_EPT; ++k) {
        int idx = base + (k << 9) + threadIdx.x;     // coalesced
        int c = (idx < E) ? col[idx] : -1;
        myc[k] = c;
        if (c >= 0) atomicAdd(&hist[c >> BSH2], 1);
    }
    __syncthreads();

    scan_512w(hist, lstart, pair);

    // reserve global space: one atomic per (block,bucket)
    for (int b = threadIdx.x; b < nb2; b += P1_TH) {
        int c = hist[b];
        int off = 0;
        if (c > 0) off = atomicAdd(&gcount[b], c);
        gbase[b] = b * CAP + off - lstart[b];        // dest = gbase[b]+sorted_idx
    }
    __syncthreads();
    for (int b = threadIdx.x; b < NB2MAX; b += P1_TH) hist[b] = lstart[b];  // cursors
    __syncthreads();

    // sort batch into LDS by bucket
    #pragma unroll
    for (int k = 0; k < P1_EPT; ++k) {
        int idx = base + (k << 9) + threadIdx.x;
        if (idx < E) {
            int c = myc[k];
            int b = c >> BSH2;
            int r = row[idx];
            int pos = atomicAdd(&hist[b], 1);
            srec[pos] = (r << BSH2) | (c & (BW2 - 1));
            sbuck[pos] = (unsigned short)b;
        }
    }
    __syncthreads();

    // dense write-out: consecutive slots -> consecutive global addresses per run
    for (int i = threadIdx.x; i < nE; i += P1_TH)
        tmp[gbase[sbuck[i]] + i] = srec[i];
}

// ---- pass 2: one block per bucket; emits sd/dis, fine-sorted ZERO-PADDED eg
//      (lists padded to x32 with sentinel row N; +64 slack slots), AND the
//      fused init (out = x, s0 = fp16(dis*x)) for its 512 nodes ----
__global__ __launch_bounds__(1024) void bin_kernel(
        const int* __restrict__ tmp, const int* __restrict__ gcount,
        int* __restrict__ eg, int2* __restrict__ sd, float* __restrict__ dis,
        const float4* __restrict__ uev, const float4* __restrict__ mev,
        float4* __restrict__ outv, uint2* __restrict__ s0v,
        int n_users, int N) {
    __shared__ int hist[BW2];
    __shared__ int padh[BW2];
    __shared__ int lstart[BW2];
    __shared__ int pair[256];
    __shared__ float sdis[BW2];
    int b = blockIdx.x;
    int cnt = gcount[b];
    int rbase = b * CAP;             // tmp region
    int ebase = b * EGCAP;           // eg region (padded)
    int c0 = b << BSH2;
    int nc = min(BW2, N - c0);
    int sent = N << 4;               // sentinel: pre-shifted zero-row index

    for (int i = threadIdx.x; i < BW2; i += BINTH) hist[i] = 0;
    __syncthreads();
    for (int i = threadIdx.x; i < cnt; i += BINTH)
        atomicAdd(&hist[tmp[rbase + i] & (BW2 - 1)], 1);
    __syncthreads();

    // padded counts (multiple of 32)
    for (int c = threadIdx.x; c < BW2; c += BINTH)
        padh[c] = (hist[c] + 31) & ~31;
    __syncthreads();

    scan_512w(padh, lstart, pair);   // prefix over padded counts

    // per-node metadata: sd = (padded start, padded count), dis = rsqrt(true deg)
    for (int c = threadIdx.x; c < nc; c += BINTH) {
        int d = hist[c];
        float dn = (d > 0) ? rsqrtf((float)d) : 0.0f;
        sd[c0 + c] = make_int2(ebase + lstart[c], padh[c]);
        dis[c0 + c] = dn;
        sdis[c] = dn;
    }
    __syncthreads();
    for (int i = threadIdx.x; i < BW2; i += BINTH) hist[i] = lstart[i];  // cursors
    __syncthreads();

    // scatter src ids (pre-shifted <<4 for gather's byte addressing)
    for (int i = threadIdx.x; i < cnt; i += BINTH) {
        int v = tmp[rbase + i];
        int pos = atomicAdd(&hist[v & (BW2 - 1)], 1);
        eg[ebase + pos] = (v >> BSH2) << 4;
    }
    __syncthreads();

    // pad-fill: cursor now = lstart+deg; fill up to lstart+padh with sentinel
    for (int i = threadIdx.x; i < BW2 * 32; i += BINTH) {
        int c = i >> 5;
        int o = i & 31;
        int st = hist[c];
        int en = lstart[c] + padh[c];
        if (st + o < en) eg[ebase + st + o] = sent;
    }
    // 64 slack slots after the last list (covers the gather's 2-deep prefetch)
    int tot = lstart[BW2 - 1] + padh[BW2 - 1];
    if (threadIdx.x < 64) eg[ebase + tot + threadIdx.x] = sent;

    // fused init for this bucket's nodes: out = x, s0 = fp16(dis*x)
    for (int i = threadIdx.x; i < nc * 16; i += BINTH) {
        int loc = i >> 4;
        int node = c0 + loc;
        int q = i & 15;
        const float4* src = (node < n_users) ? (uev + (long long)node * 16)
                                             : (mev + (long long)(node - n_users) * 16);
        float4 v = src[q];
        outv[(long long)node * 16 + q] = v;
        float dn = sdis[loc];
        pk_u w0, w1;
        w0.h[0] = (half_t)(v.x * dn); w0.h[1] = (half_t)(v.y * dn);
        w1.h[0] = (half_t)(v.z * dn); w1.h[1] = (half_t)(v.w * dn);
        s0v[(long long)node * 16 + q] = make_uint2(w0.u, w1.u);
    }
}

// ---------------- pull propagate: 8 lanes/row (dwordx4), 8 edge phases --------
// lane l: p=l&7 owns dims 8p..8p+7 (one uint4/row); h=l>>3 owns edge (j+8k+h).
// Lists zero-padded to x32 (sentinel row N = zeros): branch-free, predicate-free.
// 2-deep eg prefetch (safe via 64 sentinel slack slots per bucket).
template <bool LAST>
__global__ __launch_bounds__(256) void gather_kernel(
        const int* __restrict__ eg, const int2* __restrict__ sd,
        const float* __restrict__ dis,
        const uint4* __restrict__ tab, uint2* __restrict__ sB,
        float4* __restrict__ outv, float scale, int N) {
    int wave = blockIdx.x * (blockDim.x >> 6) + (threadIdx.x >> 6);
    if (wave >= N) return;
    int l = threadIdx.x & 63;
    int p = l & 7;
    int h = l >> 3;
    unsigned pb = (unsigned)p << 4;          // byte offset of this lane's uint4
    const char* tb = (const char*)tab;

    int2 se = sd[wave];
    int j = se.x;
    int e = se.x + se.y;                     // se.y = padded count (x32)
    pk_u a0, a1, a2, a3;
    a0.u = 0; a1.u = 0; a2.u = 0; a3.u = 0;

    if (j < e) {
        int r0 = eg[j + h];
        int r1 = eg[j + 8 + h];
        int r2 = eg[j + 16 + h];
        int r3 = eg[j + 24 + h];
        for (; j < e; j += 32) {
            int n0 = eg[j + 32 + h];         // prefetch next chunk (slack-safe)
            int n1 = eg[j + 40 + h];
            int n2 = eg[j + 48 + h];
            int n3 = eg[j + 56 + h];
            // eg stores src<<4; (r<<3)+pb = src*128 + p*16
            uint4 v0 = *(const uint4*)(tb + ((unsigned)(r0 << 3) + pb));
            uint4 v1 = *(const uint4*)(tb + ((unsigned)(r1 << 3) + pb));
            uint4 v2 = *(const uint4*)(tb + ((unsigned)(r2 << 3) + pb));
            uint4 v3 = *(const uint4*)(tb + ((unsigned)(r3 << 3) + pb));
            pk_u t;
            t.u = v0.x; a0.h += t.h; t.u = v0.y; a1.h += t.h;
            t.u = v0.z; a2.h += t.h; t.u = v0.w; a3.h += t.h;
            t.u = v1.x; a0.h += t.h; t.u = v1.y; a1.h += t.h;
            t.u = v1.z; a2.h += t.h; t.u = v1.w; a3.h += t.h;
            t.u = v2.x; a0.h += t.h; t.u = v2.y; a1.h += t.h;
            t.u = v2.z; a2.h += t.h; t.u = v2.w; a3.h += t.h;
            t.u = v3.x; a0.h += t.h; t.u = v3.y; a1.h += t.h;
            t.u = v3.z; a2.h += t.h; t.u = v3.w; a3.h += t.h;
            r0 = n0; r1 = n1; r2 = n2; r3 = n3;
        }
    }

    // reduce across the 8 edge-phases (packed); all lanes end with full sums
    #pragma unroll
    for (int m = 8; m <= 32; m <<= 1) {
        pk_u t;
        t.u = (unsigned int)__shfl_xor((int)a0.u, m); a0.h += t.h;
        t.u = (unsigned int)__shfl_xor((int)a1.u, m); a1.h += t.h;
        t.u = (unsigned int)__shfl_xor((int)a2.u, m); a2.h += t.h;
        t.u = (unsigned int)__shfl_xor((int)a3.u, m); a3.h += t.h;
    }

    if (h < 2) {                             // 16 lanes write the 64-dim row
        pk_u x0 = h ? a2 : a0;
        pk_u x1 = h ? a3 : a1;
        float dc = dis[wave];
        float g0 = dc * (float)x0.h[0];
        float g1 = dc * (float)x0.h[1];
        float g2 = dc * (float)x1.h[0];
        float g3 = dc * (float)x1.h[1];
        long long o = (long long)wave * 16 + p * 2 + h;
        float4 v = outv[o];
        v.x = (v.x + g0) * scale;
        v.y = (v.y + g1) * scale;
        v.z = (v.z + g2) * scale;
        v.w = (v.w + g3) * scale;
        outv[o] = v;
        if (!LAST) {
            pk_u w0, w1;
            w0.h[0] = (half_t)(dc * g0); w0.h[1] = (half_t)(dc * g1);
            w1.h[0] = (half_t)(dc * g2); w1.h[1] = (half_t)(dc * g3);
            sB[o] = make_uint2(w0.u, w1.u);
        }
    }
}

extern "C" void kernel_launch(void* const* d_in, const int* in_sizes, int n_in,
                              void* d_out, int out_size, void* d_ws, size_t ws_size,
                              hipStream_t stream) {
    const int*   edge = (const int*)d_in[0];    // [2, E]: row then col
    const float* ue   = (const float*)d_in[2];
    const float* me   = (const float*)d_in[3];
    float*       out  = (float*)d_out;

    const int E        = in_sizes[0] / 2;
    const int n_users  = in_sizes[2] / EMB;
    const int n_movies = in_sizes[3] / EMB;
    const int N        = n_users + n_movies;
    const int* row = edge;
    const int* col = edge + E;
    const int nb2 = (N + BW2 - 1) >> BSH2;      // 293 coarse buckets

    // workspace layout
    char* ws = (char*)d_ws;
    auto align_up = [](size_t v) { return (v + 255) & ~(size_t)255; };
    int*    gcount = (int*)ws;    ws += align_up((size_t)NB2MAX * sizeof(int));
    int2*   sd     = (int2*)ws;   ws += align_up((size_t)N * sizeof(int2));
    float*  dis    = (float*)ws;  ws += align_up((size_t)N * sizeof(float));
    int*    tmp    = (int*)ws;    ws += align_up((size_t)nb2 * CAP * sizeof(int));
    int*    eg     = (int*)ws;    ws += align_up((size_t)nb2 * EGCAP * sizeof(int));
    half_t* sA     = (half_t*)ws; ws += align_up((size_t)(N + 1) * EMB * sizeof(half_t));
    half_t* sB     = (half_t*)ws; ws += align_up((size_t)(N + 1) * EMB * sizeof(half_t));

    // two-pass counting sort -> padded CSR (deg/dis/init all fused into pass 2)
    hipMemsetAsync(gcount, 0, (size_t)NB2MAX * sizeof(int), stream);
    hipMemsetAsync(sA + (size_t)N * EMB, 0, EMB * sizeof(half_t), stream);  // zero row
    hipMemsetAsync(sB + (size_t)N * EMB, 0, EMB * sizeof(half_t), stream);  // zero row
    part_kernel<<<(E + P1_BATCH - 1) / P1_BATCH, P1_TH, 0, stream>>>(
        row, col, gcount, tmp, E, nb2);
    bin_kernel<<<nb2, BINTH, 0, stream>>>(
        tmp, gcount, eg, sd, dis,
        (const float4*)ue, (const float4*)me, (float4*)out, (uint2*)sA,
        n_users, N);

    // 3 propagation layers (atomic-free pull, packed fp16)
    const int waves_per_block = 4;   // 256 threads
    const int gblocks = (N + waves_per_block - 1) / waves_per_block;
    gather_kernel<false><<<gblocks, 256, 0, stream>>>(
        eg, sd, dis, (const uint4*)sA, (uint2*)sB, (float4*)out, 1.0f, N);
    gather_kernel<false><<<gblocks, 256, 0, stream>>>(
        eg, sd, dis, (const uint4*)sB, (uint2*)sA, (float4*)out, 1.0f, N);
    gather_kernel<true><<<gblocks, 256, 0, stream>>>(
        eg, sd, dis, (const uint4*)sA, (uint2*)sB, (float4*)out,
        1.0f / (NLAYERS + 1), N);
}

// Round 3
// 487.699 us; speedup vs baseline: 1.0946x; 1.0107x over previous
//
#include <hip/hip_runtime.h>

typedef _Float16 half_t;
typedef _Float16 half2_t __attribute__((ext_vector_type(2)));
union pk_u { unsigned int u; half2_t h; };

#define EMB 64
#define NLAYERS 3
#define BSH2 9
#define BW2 512            // nodes per coarse bucket
#define NB2MAX 512         // max bucket count (N<=262144)
#define GSPREAD 32         // gcount: one counter per 128-B line (atomic line-conflict fix)
#define CAP 20480          // tmp region per bucket (avg 17065 edges, +20%)
#define EGCAP 34816        // eg region per bucket: 64-padded lists, 512*64=32768 + slack
#define P1_BATCH 4096
#define P1_TH 512
#define P1_EPT 8           // edges per thread in part_kernel (4096/512)
#define BINTH 1024

// ---- 512-entry exclusive scan of in[] -> lstart[]; first 256 threads active ----
__device__ inline void scan_512w(const int* __restrict__ in, int* __restrict__ lstart,
                                 int* __restrict__ pair) {
    int t = threadIdx.x;
    int a0 = 0, a1 = 0;
    if (t < 256) { a0 = in[2 * t]; a1 = in[2 * t + 1]; pair[t] = a0 + a1; }
    __syncthreads();
    for (int off = 1; off < 256; off <<= 1) {
        int u = 0;
        if (t < 256 && t >= off) u = pair[t - off];
        __syncthreads();
        if (t < 256) pair[t] += u;
        __syncthreads();
    }
    if (t < 256) {
        lstart[2 * t]     = pair[t] - a0 - a1;
        lstart[2 * t + 1] = pair[t] - a1;
    }
    __syncthreads();
}

// ---- pass 1: partition edges into coarse buckets, LDS-sorted dense writes ----
__global__ __launch_bounds__(512) void part_kernel(
        const int* __restrict__ row, const int* __restrict__ col,
        int* __restrict__ gcount, int* __restrict__ tmp, int E, int nb2) {
    __shared__ int hist[NB2MAX];
    __shared__ int lstart[NB2MAX];
    __shared__ int gbase[NB2MAX];
    __shared__ int pair[256];
    __shared__ int srec[P1_BATCH];            // batch sorted by bucket
    __shared__ unsigned short sbuck[P1_BATCH];

    int base = blockIdx.x * P1_BATCH;
    int nE = min(P1_BATCH, E - base);

    for (int i = threadIdx.x; i < NB2MAX; i += P1_TH) hist[i] = 0;
    __syncthreads();

    // histogram (keep cols in registers)
    int myc[P1_EPT];
    #pragma unroll
    for (int k = 0; k < P1_EPT; ++k) {
        int idx = base + (k << 9) + threadIdx.x;     // coalesced
        int c = (idx < E) ? col[idx] : -1;
        myc[k] = c;
        if (c >= 0) atomicAdd(&hist[c >> BSH2], 1);
    }
    __syncthreads();

    scan_512w(hist, lstart, pair);

    // reserve global space: one atomic per (block,bucket); counters line-spread
    for (int b = threadIdx.x; b < nb2; b += P1_TH) {
        int c = hist[b];
        int off = 0;
        if (c > 0) off = atomicAdd(&gcount[b * GSPREAD], c);
        gbase[b] = b * CAP + off - lstart[b];        // dest = gbase[b]+sorted_idx
    }
    __syncthreads();
    for (int b = threadIdx.x; b < NB2MAX; b += P1_TH) hist[b] = lstart[b];  // cursors
    __syncthreads();

    // sort batch into LDS by bucket
    #pragma unroll
    for (int k = 0; k < P1_EPT; ++k) {
        int idx = base + (k << 9) + threadIdx.x;
        if (idx < E) {
            int c = myc[k];
            int b = c >> BSH2;
            int r = row[idx];
            int pos = atomicAdd(&hist[b], 1);
            srec[pos] = (r << BSH2) | (c & (BW2 - 1));
            sbuck[pos] = (unsigned short)b;
        }
    }
    __syncthreads();

    // dense write-out: consecutive slots -> consecutive global addresses per run
    for (int i = threadIdx.x; i < nE; i += P1_TH)
        tmp[gbase[sbuck[i]] + i] = srec[i];
}

// ---- pass 2: one block per bucket; emits sd/dis, fine-sorted ZERO-PADDED eg
//      (lists padded to x64 with sentinel row N; byte offsets pre-shifted <<7),
//      AND the fused s0 init (s0 = fp16(dis*x)) for its 512 nodes ----
__global__ __launch_bounds__(1024) void bin_kernel(
        const int* __restrict__ tmp, const int* __restrict__ gcount,
        int* __restrict__ eg, int2* __restrict__ sd, float* __restrict__ dis,
        const float4* __restrict__ uev, const float4* __restrict__ mev,
        uint2* __restrict__ s0v,
        int n_users, int N) {
    __shared__ int hist[BW2];
    __shared__ int padh[BW2];
    __shared__ int lstart[BW2];
    __shared__ int pair[256];
    __shared__ float sdis[BW2];
    int b = blockIdx.x;
    int cnt = gcount[b * GSPREAD];
    int rbase = b * CAP;             // tmp region
    int ebase = b * EGCAP;           // eg region (padded)
    int c0 = b << BSH2;
    int nc = min(BW2, N - c0);
    int sent = N << 7;               // sentinel: byte offset of zero row

    for (int i = threadIdx.x; i < BW2; i += BINTH) hist[i] = 0;
    __syncthreads();
    for (int i = threadIdx.x; i < cnt; i += BINTH)
        atomicAdd(&hist[tmp[rbase + i] & (BW2 - 1)], 1);
    __syncthreads();

    // padded counts (multiple of 64 -> straight-line gather body)
    for (int c = threadIdx.x; c < BW2; c += BINTH)
        padh[c] = (hist[c] + 63) & ~63;
    __syncthreads();

    scan_512w(padh, lstart, pair);   // prefix over padded counts

    // per-node metadata: sd = (padded start, padded count), dis = rsqrt(true deg)
    for (int c = threadIdx.x; c < nc; c += BINTH) {
        int d = hist[c];
        float dn = (d > 0) ? rsqrtf((float)d) : 0.0f;
        sd[c0 + c] = make_int2(ebase + lstart[c], padh[c]);
        dis[c0 + c] = dn;
        sdis[c] = dn;
    }
    __syncthreads();
    for (int i = threadIdx.x; i < BW2; i += BINTH) hist[i] = lstart[i];  // cursors
    __syncthreads();

    // scatter src byte-offsets (src*128, ready for gather addressing)
    for (int i = threadIdx.x; i < cnt; i += BINTH) {
        int v = tmp[rbase + i];
        int pos = atomicAdd(&hist[v & (BW2 - 1)], 1);
        eg[ebase + pos] = (v >> BSH2) << 7;
    }
    __syncthreads();

    // pad-fill: cursor = lstart+deg; fill up to lstart+padh with sentinel
    // (per-node serial: handles any degree, avg ~31 fills/node)
    for (int c = threadIdx.x; c < nc; c += BINTH) {
        int en = lstart[c] + padh[c];
        for (int ppos = hist[c]; ppos < en; ++ppos) eg[ebase + ppos] = sent;
    }

    // fused s0 init for this bucket's nodes: s0 = fp16(dis*x)
    for (int i = threadIdx.x; i < nc * 16; i += BINTH) {
        int loc = i >> 4;
        int node = c0 + loc;
        int q = i & 15;
        const float4* src = (node < n_users) ? (uev + (long long)node * 16)
                                             : (mev + (long long)(node - n_users) * 16);
        float4 v = src[q];
        float dn = sdis[loc];
        pk_u w0, w1;
        w0.h[0] = (half_t)(v.x * dn); w0.h[1] = (half_t)(v.y * dn);
        w1.h[0] = (half_t)(v.z * dn); w1.h[1] = (half_t)(v.w * dn);
        s0v[(long long)node * 16 + q] = make_uint2(w0.u, w1.u);
    }
}

// ---------------- pull propagate: 8 lanes/row (dwordx4), 8 edge phases --------
// lane l: p=l&7 owns dims 8p..8p+7 (one uint4/row); h=l>>3 owns edge (j+8k+h).
// Lists zero-padded to x64: straight-line body, 8 eg + 8 table loads in flight.
// LAYER 1: reads s0, writes s1 + u1=fp16(a1) (u1 stride-16 rows, aliases tmp)
// LAYER 2: reads s1, writes s2 + u2=fp16(a2) (u2 stride-32 rows, lives in out)
// LAYER 3: reads s2 + x + u1 + u2, writes out = (x+u1+u2+a3)/4
template <int LAYER>
__global__ __launch_bounds__(256) void gather_kernel(
        const int* __restrict__ eg, const int2* __restrict__ sd,
        const float* __restrict__ dis,
        const uint4* __restrict__ tab, uint2* __restrict__ sOut,
        uint2* __restrict__ uOut,
        const uint2* __restrict__ u1, const uint2* __restrict__ u2,
        const float4* __restrict__ uev, const float4* __restrict__ mev,
        float4* __restrict__ outv, int n_users, int N) {
    int wave = blockIdx.x * (blockDim.x >> 6) + (threadIdx.x >> 6);
    if (wave >= N) return;
    int l = threadIdx.x & 63;
    int p = l & 7;
    int h = l >> 3;
    unsigned pb = (unsigned)p << 4;          // byte offset of this lane's uint4
    const char* tb = (const char*)tab;

    int2 se = sd[wave];
    int j = se.x;
    int e = se.x + se.y;                     // se.y = padded count (x64)
    pk_u a0, a1, a2, a3;
    a0.u = 0; a1.u = 0; a2.u = 0; a3.u = 0;

    for (; j < e; j += 64) {
        int r0 = eg[j + h];                  // 8 independent index loads
        int r1 = eg[j + 8 + h];
        int r2 = eg[j + 16 + h];
        int r3 = eg[j + 24 + h];
        int r4 = eg[j + 32 + h];
        int r5 = eg[j + 40 + h];
        int r6 = eg[j + 48 + h];
        int r7 = eg[j + 56 + h];
        // eg stores src*128 (byte offset); + pb = this lane's uint4
        uint4 v0 = *(const uint4*)(tb + ((unsigned)r0 + pb));
        uint4 v1 = *(const uint4*)(tb + ((unsigned)r1 + pb));
        uint4 v2 = *(const uint4*)(tb + ((unsigned)r2 + pb));
        uint4 v3 = *(const uint4*)(tb + ((unsigned)r3 + pb));
        uint4 v4 = *(const uint4*)(tb + ((unsigned)r4 + pb));
        uint4 v5 = *(const uint4*)(tb + ((unsigned)r5 + pb));
        uint4 v6 = *(const uint4*)(tb + ((unsigned)r6 + pb));
        uint4 v7 = *(const uint4*)(tb + ((unsigned)r7 + pb));
        pk_u t;
        t.u = v0.x; a0.h += t.h; t.u = v0.y; a1.h += t.h;
        t.u = v0.z; a2.h += t.h; t.u = v0.w; a3.h += t.h;
        t.u = v1.x; a0.h += t.h; t.u = v1.y; a1.h += t.h;
        t.u = v1.z; a2.h += t.h; t.u = v1.w; a3.h += t.h;
        t.u = v2.x; a0.h += t.h; t.u = v2.y; a1.h += t.h;
        t.u = v2.z; a2.h += t.h; t.u = v2.w; a3.h += t.h;
        t.u = v3.x; a0.h += t.h; t.u = v3.y; a1.h += t.h;
        t.u = v3.z; a2.h += t.h; t.u = v3.w; a3.h += t.h;
        t.u = v4.x; a0.h += t.h; t.u = v4.y; a1.h += t.h;
        t.u = v4.z; a2.h += t.h; t.u = v4.w; a3.h += t.h;
        t.u = v5.x; a0.h += t.h; t.u = v5.y; a1.h += t.h;
        t.u = v5.z; a2.h += t.h; t.u = v5.w; a3.h += t.h;
        t.u = v6.x; a0.h += t.h; t.u = v6.y; a1.h += t.h;
        t.u = v6.z; a2.h += t.h; t.u = v6.w; a3.h += t.h;
        t.u = v7.x; a0.h += t.h; t.u = v7.y; a1.h += t.h;
        t.u = v7.z; a2.h += t.h; t.u = v7.w; a3.h += t.h;
    }

    // reduce across the 8 edge-phases (packed); all lanes end with full sums
    #pragma unroll
    for (int m = 8; m <= 32; m <<= 1) {
        pk_u t;
        t.u = (unsigned int)__shfl_xor((int)a0.u, m); a0.h += t.h;
        t.u = (unsigned int)__shfl_xor((int)a1.u, m); a1.h += t.h;
        t.u = (unsigned int)__shfl_xor((int)a2.u, m); a2.h += t.h;
        t.u = (unsigned int)__shfl_xor((int)a3.u, m); a3.h += t.h;
    }

    if (h < 2) {                             // 16 lanes handle the 64-dim row
        pk_u x0 = h ? a2 : a0;
        pk_u x1 = h ? a3 : a1;
        float dc = dis[wave];
        float g0 = dc * (float)x0.h[0];
        float g1 = dc * (float)x0.h[1];
        float g2 = dc * (float)x1.h[0];
        float g3 = dc * (float)x1.h[1];
        int q = p * 2 + h;
        long long o16 = (long long)wave * 16 + q;
        if (LAYER < 3) {
            pk_u w0, w1, uw0, uw1;
            w0.h[0] = (half_t)(dc * g0); w0.h[1] = (half_t)(dc * g1);
            w1.h[0] = (half_t)(dc * g2); w1.h[1] = (half_t)(dc * g3);
            uw0.h[0] = (half_t)g0; uw0.h[1] = (half_t)g1;
            uw1.h[0] = (half_t)g2; uw1.h[1] = (half_t)g3;
            sOut[o16] = make_uint2(w0.u, w1.u);
            long long uo = (LAYER == 1) ? o16 : ((long long)wave * 32 + q);
            uOut[uo] = make_uint2(uw0.u, uw1.u);
        } else {
            const float4* src = (wave < n_users) ? (uev + (long long)wave * 16)
                                                 : (mev + (long long)(wave - n_users) * 16);
            float4 xv = src[q];
            uint2 ua2 = u1[o16];
            uint2 ub2 = u2[(long long)wave * 32 + q];
            pk_u pa, pb2, pc, pd;
            pa.u = ua2.x; pb2.u = ua2.y; pc.u = ub2.x; pd.u = ub2.y;
            float4 r;
            r.x = (xv.x + (float)pa.h[0]  + (float)pc.h[0] + g0) * 0.25f;
            r.y = (xv.y + (float)pa.h[1]  + (float)pc.h[1] + g1) * 0.25f;
            r.z = (xv.z + (float)pb2.h[0] + (float)pd.h[0] + g2) * 0.25f;
            r.w = (xv.w + (float)pb2.h[1] + (float)pd.h[1] + g3) * 0.25f;
            outv[o16] = r;                   // same-row in-place over u2: load-before-store
        }
    }
}

extern "C" void kernel_launch(void* const* d_in, const int* in_sizes, int n_in,
                              void* d_out, int out_size, void* d_ws, size_t ws_size,
                              hipStream_t stream) {
    const int*   edge = (const int*)d_in[0];    // [2, E]: row then col
    const float* ue   = (const float*)d_in[2];
    const float* me   = (const float*)d_in[3];
    float*       out  = (float*)d_out;

    const int E        = in_sizes[0] / 2;
    const int n_users  = in_sizes[2] / EMB;
    const int n_movies = in_sizes[3] / EMB;
    const int N        = n_users + n_movies;
    const int* row = edge;
    const int* col = edge + E;
    const int nb2 = (N + BW2 - 1) >> BSH2;      // 293 coarse buckets

    // workspace layout
    char* ws = (char*)d_ws;
    auto align_up = [](size_t v) { return (v + 255) & ~(size_t)255; };
    int*    gcount = (int*)ws;    ws += align_up((size_t)NB2MAX * GSPREAD * sizeof(int));
    int2*   sd     = (int2*)ws;   ws += align_up((size_t)N * sizeof(int2));
    float*  dis    = (float*)ws;  ws += align_up((size_t)N * sizeof(float));
    int*    tmp    = (int*)ws;    ws += align_up((size_t)nb2 * CAP * sizeof(int));
    int*    eg     = (int*)ws;    ws += align_up((size_t)nb2 * EGCAP * sizeof(int));
    half_t* sA     = (half_t*)ws; ws += align_up((size_t)(N + 1) * EMB * sizeof(half_t));
    half_t* sB     = (half_t*)ws; ws += align_up((size_t)(N + 1) * EMB * sizeof(half_t));
    // u1 = fp16(a1), stride-16 rows: aliases tmp (dead after bin_kernel)
    uint2* u1 = (uint2*)tmp;
    // u2 = fp16(a2), stride-32 rows: lives in the (unwritten) out buffer
    uint2* u2 = (uint2*)out;

    // two-pass counting sort -> padded CSR (deg/dis/s0 all fused into pass 2)
    hipMemsetAsync(gcount, 0, (size_t)NB2MAX * GSPREAD * sizeof(int), stream);
    hipMemsetAsync(sA + (size_t)N * EMB, 0, EMB * sizeof(half_t), stream);  // zero row
    hipMemsetAsync(sB + (size_t)N * EMB, 0, EMB * sizeof(half_t), stream);  // zero row
    part_kernel<<<(E + P1_BATCH - 1) / P1_BATCH, P1_TH, 0, stream>>>(
        row, col, gcount, tmp, E, nb2);
    bin_kernel<<<nb2, BINTH, 0, stream>>>(
        tmp, gcount, eg, sd, dis,
        (const float4*)ue, (const float4*)me, (uint2*)sA,
        n_users, N);

    // 3 propagation layers (atomic-free pull, packed fp16, no out RMW)
    const int waves_per_block = 4;   // 256 threads
    const int gblocks = (N + waves_per_block - 1) / waves_per_block;
    gather_kernel<1><<<gblocks, 256, 0, stream>>>(
        eg, sd, dis, (const uint4*)sA, (uint2*)sB, u1,
        nullptr, nullptr, nullptr, nullptr, nullptr, n_users, N);
    gather_kernel<2><<<gblocks, 256, 0, stream>>>(
        eg, sd, dis, (const uint4*)sB, (uint2*)sA, u2,
        nullptr, nullptr, nullptr, nullptr, nullptr, n_users, N);
    gather_kernel<3><<<gblocks, 256, 0, stream>>>(
        eg, sd, dis, (const uint4*)sA, nullptr, nullptr,
        (const uint2*)u1, (const uint2*)u2,
        (const float4*)ue, (const float4*)me, (float4*)out, n_users, N);
}

// Round 4
// 486.041 us; speedup vs baseline: 1.0983x; 1.0034x over previous
//
#include <hip/hip_runtime.h>

typedef _Float16 half_t;
typedef _Float16 half2_t __attribute__((ext_vector_type(2)));
union pk_u { unsigned int u; half2_t h; };

#define EMB 64
#define NLAYERS 3
#define BSH2 8
#define BW2 256            // nodes per coarse bucket (halved: fixes bin tail)
#define NB2MAX 1024        // max bucket count (N<=262144)
#define GSPREAD 32         // gcount: one counter per 128-B line
#define CAP 10240          // tmp region per bucket (avg 8533 edges, +20%)
#define EGCAP 16384        // eg region per bucket: 32-padded lists (avg ~12.6K) + slack
#define P1_BATCH 4096
#define P1_TH 512
#define P1_EPT 8           // edges per thread in part_kernel (4096/512)
#define BINTH 512

// ---- NE-entry exclusive scan of in[] -> lstart[]; NE/2 threads active ----
template <int NE>
__device__ inline void scan_pow2(const int* __restrict__ in, int* __restrict__ lstart,
                                 int* __restrict__ pair) {
    const int H = NE / 2;
    int t = threadIdx.x;
    int a0 = 0, a1 = 0;
    if (t < H) { a0 = in[2 * t]; a1 = in[2 * t + 1]; pair[t] = a0 + a1; }
    __syncthreads();
    for (int off = 1; off < H; off <<= 1) {
        int u = 0;
        if (t < H && t >= off) u = pair[t - off];
        __syncthreads();
        if (t < H) pair[t] += u;
        __syncthreads();
    }
    if (t < H) {
        lstart[2 * t]     = pair[t] - a0 - a1;
        lstart[2 * t + 1] = pair[t] - a1;
    }
    __syncthreads();
}

// ---- pass 1: partition edges into coarse buckets, LDS-sorted dense writes ----
__global__ __launch_bounds__(512) void part_kernel(
        const int* __restrict__ row, const int* __restrict__ col,
        int* __restrict__ gcount, int* __restrict__ tmp, int E, int nb2) {
    __shared__ int hist[NB2MAX];
    __shared__ int lstart[NB2MAX];
    __shared__ int gbase[NB2MAX];
    __shared__ int pair[NB2MAX / 2];
    __shared__ int srec[P1_BATCH];            // batch sorted by bucket
    __shared__ unsigned short sbuck[P1_BATCH];

    int base = blockIdx.x * P1_BATCH;
    int nE = min(P1_BATCH, E - base);

    for (int i = threadIdx.x; i < NB2MAX; i += P1_TH) hist[i] = 0;
    __syncthreads();

    // histogram (keep cols in registers)
    int myc[P1_EPT];
    #pragma unroll
    for (int k = 0; k < P1_EPT; ++k) {
        int idx = base + (k << 9) + threadIdx.x;     // coalesced
        int c = (idx < E) ? col[idx] : -1;
        myc[k] = c;
        if (c >= 0) atomicAdd(&hist[c >> BSH2], 1);
    }
    __syncthreads();

    scan_pow2<NB2MAX>(hist, lstart, pair);

    // reserve global space: one atomic per (block,bucket); counters line-spread
    for (int b = threadIdx.x; b < nb2; b += P1_TH) {
        int c = hist[b];
        int off = 0;
        if (c > 0) off = atomicAdd(&gcount[b * GSPREAD], c);
        gbase[b] = b * CAP + off - lstart[b];        // dest = gbase[b]+sorted_idx
    }
    __syncthreads();
    for (int b = threadIdx.x; b < NB2MAX; b += P1_TH) hist[b] = lstart[b];  // cursors
    __syncthreads();

    // sort batch into LDS by bucket
    #pragma unroll
    for (int k = 0; k < P1_EPT; ++k) {
        int idx = base + (k << 9) + threadIdx.x;
        if (idx < E) {
            int c = myc[k];
            int b = c >> BSH2;
            int r = row[idx];
            int pos = atomicAdd(&hist[b], 1);
            srec[pos] = (r << BSH2) | (c & (BW2 - 1));
            sbuck[pos] = (unsigned short)b;
        }
    }
    __syncthreads();

    // dense write-out: consecutive slots -> consecutive global addresses per run
    for (int i = threadIdx.x; i < nE; i += P1_TH)
        tmp[gbase[sbuck[i]] + i] = srec[i];
}

// ---- pass 2: one block per 256-node bucket (586 blocks -> all co-resident, no
//      makespan tail); emits sd/dis, fine-sorted ZERO-PADDED eg (lists padded to
//      x32 with sentinel row N; byte offsets pre-shifted <<7), AND the fused s0
//      init (s0 = fp16(dis*x)) for its nodes ----
__global__ __launch_bounds__(512) void bin_kernel(
        const int* __restrict__ tmp, const int* __restrict__ gcount,
        int* __restrict__ eg, int2* __restrict__ sd, float* __restrict__ dis,
        const float4* __restrict__ uev, const float4* __restrict__ mev,
        uint2* __restrict__ s0v,
        int n_users, int N) {
    __shared__ int hist[BW2];
    __shared__ int padh[BW2];
    __shared__ int lstart[BW2];
    __shared__ int pair[BW2 / 2];
    __shared__ float sdis[BW2];
    int b = blockIdx.x;
    int cnt = gcount[b * GSPREAD];
    int rbase = b * CAP;             // tmp region
    int ebase = b * EGCAP;           // eg region (padded)
    int c0 = b << BSH2;
    int nc = min(BW2, N - c0);
    int sent = N << 7;               // sentinel: byte offset of zero row

    for (int i = threadIdx.x; i < BW2; i += BINTH) hist[i] = 0;
    __syncthreads();
    for (int i = threadIdx.x; i < cnt; i += BINTH)
        atomicAdd(&hist[tmp[rbase + i] & (BW2 - 1)], 1);
    __syncthreads();

    // padded counts (multiple of 32)
    for (int c = threadIdx.x; c < BW2; c += BINTH)
        padh[c] = (hist[c] + 31) & ~31;
    __syncthreads();

    scan_pow2<BW2>(padh, lstart, pair);   // prefix over padded counts

    // per-node metadata: sd = (padded start, padded count), dis = rsqrt(true deg)
    for (int c = threadIdx.x; c < nc; c += BINTH) {
        int d = hist[c];
        float dn = (d > 0) ? rsqrtf((float)d) : 0.0f;
        sd[c0 + c] = make_int2(ebase + lstart[c], padh[c]);
        dis[c0 + c] = dn;
        sdis[c] = dn;
    }
    __syncthreads();
    for (int i = threadIdx.x; i < BW2; i += BINTH) hist[i] = lstart[i];  // cursors
    __syncthreads();

    // scatter src byte-offsets (src*128, ready for gather addressing)
    for (int i = threadIdx.x; i < cnt; i += BINTH) {
        int v = tmp[rbase + i];
        int pos = atomicAdd(&hist[v & (BW2 - 1)], 1);
        eg[ebase + pos] = (v >> BSH2) << 7;
    }
    __syncthreads();

    // pad-fill: cursor = lstart+deg; fill up to lstart+padh (<32/node) with sentinel
    for (int i = threadIdx.x; i < BW2 * 32; i += BINTH) {
        int c = i >> 5;
        int o = i & 31;
        int st = hist[c];
        int en = lstart[c] + padh[c];
        if (st + o < en) eg[ebase + st + o] = sent;
    }
    // 64 slack slots after the last list (covers the gather's 2-deep prefetch)
    int tot = lstart[BW2 - 1] + padh[BW2 - 1];
    if (threadIdx.x < 64) eg[ebase + tot + threadIdx.x] = sent;

    // fused s0 init for this bucket's nodes: s0 = fp16(dis*x)
    for (int i = threadIdx.x; i < nc * 16; i += BINTH) {
        int loc = i >> 4;
        int node = c0 + loc;
        int q = i & 15;
        const float4* src = (node < n_users) ? (uev + (long long)node * 16)
                                             : (mev + (long long)(node - n_users) * 16);
        float4 v = src[q];
        float dn = sdis[loc];
        pk_u w0, w1;
        w0.h[0] = (half_t)(v.x * dn); w0.h[1] = (half_t)(v.y * dn);
        w1.h[0] = (half_t)(v.z * dn); w1.h[1] = (half_t)(v.w * dn);
        s0v[(long long)node * 16 + q] = make_uint2(w0.u, w1.u);
    }
}

// ---------------- pull propagate: 8 lanes/row (dwordx4), 8 edge phases --------
// lane l: p=l&7 owns dims 8p..8p+7 (one uint4/row); h=l>>3 owns edge (j+8k+h).
// Lists zero-padded to x32 (sentinel row N = zeros): branch-free, predicate-free.
// 2-deep eg prefetch (safe via 64 sentinel slack slots per bucket).
// LAYER 1: reads s0, writes s1 + u1=fp16(a1) (u1 stride-16 rows, aliases tmp)
// LAYER 2: reads s1, writes s2 + u2=fp16(a2) (u2 stride-32 rows, lives in out)
// LAYER 3: reads s2 + x + u1 + u2, writes out = (x+u1+u2+a3)/4
template <int LAYER>
__global__ __launch_bounds__(256) void gather_kernel(
        const int* __restrict__ eg, const int2* __restrict__ sd,
        const float* __restrict__ dis,
        const uint4* __restrict__ tab, uint2* __restrict__ sOut,
        uint2* __restrict__ uOut,
        const uint2* __restrict__ u1, const uint2* __restrict__ u2,
        const float4* __restrict__ uev, const float4* __restrict__ mev,
        float4* __restrict__ outv, int n_users, int N) {
    int wave = blockIdx.x * (blockDim.x >> 6) + (threadIdx.x >> 6);
    if (wave >= N) return;
    int l = threadIdx.x & 63;
    int p = l & 7;
    int h = l >> 3;
    unsigned pb = (unsigned)p << 4;          // byte offset of this lane's uint4
    const char* tb = (const char*)tab;

    int2 se = sd[wave];
    int j = se.x;
    int e = se.x + se.y;                     // se.y = padded count (x32)
    pk_u a0, a1, a2, a3;
    a0.u = 0; a1.u = 0; a2.u = 0; a3.u = 0;

    if (j < e) {
        int r0 = eg[j + h];
        int r1 = eg[j + 8 + h];
        int r2 = eg[j + 16 + h];
        int r3 = eg[j + 24 + h];
        for (; j < e; j += 32) {
            int n0 = eg[j + 32 + h];         // prefetch next chunk (slack-safe)
            int n1 = eg[j + 40 + h];
            int n2 = eg[j + 48 + h];
            int n3 = eg[j + 56 + h];
            // eg stores src*128 (byte offset); + pb = this lane's uint4
            uint4 v0 = *(const uint4*)(tb + ((unsigned)r0 + pb));
            uint4 v1 = *(const uint4*)(tb + ((unsigned)r1 + pb));
            uint4 v2 = *(const uint4*)(tb + ((unsigned)r2 + pb));
            uint4 v3 = *(const uint4*)(tb + ((unsigned)r3 + pb));
            pk_u t;
            t.u = v0.x; a0.h += t.h; t.u = v0.y; a1.h += t.h;
            t.u = v0.z; a2.h += t.h; t.u = v0.w; a3.h += t.h;
            t.u = v1.x; a0.h += t.h; t.u = v1.y; a1.h += t.h;
            t.u = v1.z; a2.h += t.h; t.u = v1.w; a3.h += t.h;
            t.u = v2.x; a0.h += t.h; t.u = v2.y; a1.h += t.h;
            t.u = v2.z; a2.h += t.h; t.u = v2.w; a3.h += t.h;
            t.u = v3.x; a0.h += t.h; t.u = v3.y; a1.h += t.h;
            t.u = v3.z; a2.h += t.h; t.u = v3.w; a3.h += t.h;
            r0 = n0; r1 = n1; r2 = n2; r3 = n3;
        }
    }

    // reduce across the 8 edge-phases (packed); all lanes end with full sums
    #pragma unroll
    for (int m = 8; m <= 32; m <<= 1) {
        pk_u t;
        t.u = (unsigned int)__shfl_xor((int)a0.u, m); a0.h += t.h;
        t.u = (unsigned int)__shfl_xor((int)a1.u, m); a1.h += t.h;
        t.u = (unsigned int)__shfl_xor((int)a2.u, m); a2.h += t.h;
        t.u = (unsigned int)__shfl_xor((int)a3.u, m); a3.h += t.h;
    }

    if (h < 2) {                             // 16 lanes handle the 64-dim row
        pk_u x0 = h ? a2 : a0;
        pk_u x1 = h ? a3 : a1;
        float dc = dis[wave];
        float g0 = dc * (float)x0.h[0];
        float g1 = dc * (float)x0.h[1];
        float g2 = dc * (float)x1.h[0];
        float g3 = dc * (float)x1.h[1];
        int q = p * 2 + h;
        long long o16 = (long long)wave * 16 + q;
        if (LAYER < 3) {
            pk_u w0, w1, uw0, uw1;
            w0.h[0] = (half_t)(dc * g0); w0.h[1] = (half_t)(dc * g1);
            w1.h[0] = (half_t)(dc * g2); w1.h[1] = (half_t)(dc * g3);
            uw0.h[0] = (half_t)g0; uw0.h[1] = (half_t)g1;
            uw1.h[0] = (half_t)g2; uw1.h[1] = (half_t)g3;
            sOut[o16] = make_uint2(w0.u, w1.u);
            long long uo = (LAYER == 1) ? o16 : ((long long)wave * 32 + q);
            uOut[uo] = make_uint2(uw0.u, uw1.u);
        } else {
            const float4* src = (wave < n_users) ? (uev + (long long)wave * 16)
                                                 : (mev + (long long)(wave - n_users) * 16);
            float4 xv = src[q];
            uint2 ua2 = u1[o16];
            uint2 ub2 = u2[(long long)wave * 32 + q];
            pk_u pa, pb2, pc, pd;
            pa.u = ua2.x; pb2.u = ua2.y; pc.u = ub2.x; pd.u = ub2.y;
            float4 r;
            r.x = (xv.x + (float)pa.h[0]  + (float)pc.h[0] + g0) * 0.25f;
            r.y = (xv.y + (float)pa.h[1]  + (float)pc.h[1] + g1) * 0.25f;
            r.z = (xv.z + (float)pb2.h[0] + (float)pd.h[0] + g2) * 0.25f;
            r.w = (xv.w + (float)pb2.h[1] + (float)pd.h[1] + g3) * 0.25f;
            outv[o16] = r;                   // same-row in-place over u2: load-before-store
        }
    }
}

extern "C" void kernel_launch(void* const* d_in, const int* in_sizes, int n_in,
                              void* d_out, int out_size, void* d_ws, size_t ws_size,
                              hipStream_t stream) {
    const int*   edge = (const int*)d_in[0];    // [2, E]: row then col
    const float* ue   = (const float*)d_in[2];
    const float* me   = (const float*)d_in[3];
    float*       out  = (float*)d_out;

    const int E        = in_sizes[0] / 2;
    const int n_users  = in_sizes[2] / EMB;
    const int n_movies = in_sizes[3] / EMB;
    const int N        = n_users + n_movies;
    const int* row = edge;
    const int* col = edge + E;
    const int nb2 = (N + BW2 - 1) >> BSH2;      // 586 coarse buckets

    // workspace layout
    char* ws = (char*)d_ws;
    auto align_up = [](size_t v) { return (v + 255) & ~(size_t)255; };
    int*    gcount = (int*)ws;    ws += align_up((size_t)NB2MAX * GSPREAD * sizeof(int));
    int2*   sd     = (int2*)ws;   ws += align_up((size_t)N * sizeof(int2));
    float*  dis    = (float*)ws;  ws += align_up((size_t)N * sizeof(float));
    int*    tmp    = (int*)ws;    ws += align_up((size_t)nb2 * CAP * sizeof(int));
    int*    eg     = (int*)ws;    ws += align_up((size_t)nb2 * EGCAP * sizeof(int));
    half_t* sA     = (half_t*)ws; ws += align_up((size_t)(N + 1) * EMB * sizeof(half_t));
    half_t* sB     = (half_t*)ws; ws += align_up((size_t)(N + 1) * EMB * sizeof(half_t));
    // u1 = fp16(a1), stride-16 rows: aliases tmp (dead after bin_kernel; 19.2<=24MB)
    uint2* u1 = (uint2*)tmp;
    // u2 = fp16(a2), stride-32 rows: lives in the (unwritten) out buffer
    uint2* u2 = (uint2*)out;

    // two-pass counting sort -> padded CSR (deg/dis/s0 all fused into pass 2)
    hipMemsetAsync(gcount, 0, (size_t)NB2MAX * GSPREAD * sizeof(int), stream);
    hipMemsetAsync(sA + (size_t)N * EMB, 0, EMB * sizeof(half_t), stream);  // zero row
    hipMemsetAsync(sB + (size_t)N * EMB, 0, EMB * sizeof(half_t), stream);  // zero row
    part_kernel<<<(E + P1_BATCH - 1) / P1_BATCH, P1_TH, 0, stream>>>(
        row, col, gcount, tmp, E, nb2);
    bin_kernel<<<nb2, BINTH, 0, stream>>>(
        tmp, gcount, eg, sd, dis,
        (const float4*)ue, (const float4*)me, (uint2*)sA,
        n_users, N);

    // 3 propagation layers (atomic-free pull, packed fp16, no out RMW)
    const int waves_per_block = 4;   // 256 threads
    const int gblocks = (N + waves_per_block - 1) / waves_per_block;
    gather_kernel<1><<<gblocks, 256, 0, stream>>>(
        eg, sd, dis, (const uint4*)sA, (uint2*)sB, u1,
        nullptr, nullptr, nullptr, nullptr, nullptr, n_users, N);
    gather_kernel<2><<<gblocks, 256, 0, stream>>>(
        eg, sd, dis, (const uint4*)sB, (uint2*)sA, u2,
        nullptr, nullptr, nullptr, nullptr, nullptr, n_users, N);
    gather_kernel<3><<<gblocks, 256, 0, stream>>>(
        eg, sd, dis, (const uint4*)sA, nullptr, nullptr,
        (const uint2*)u1, (const uint2*)u2,
        (const float4*)ue, (const float4*)me, (float4*)out, n_users, N);
}